// Round 1
// baseline (417.263 us; speedup 1.0000x reference)
//
#include <hip/hip_runtime.h>
#include <math.h>

#define HW 240
#define PITCH 241          // +1 complex pad to break LDS bank conflicts on transposed reads
#define IMG_PIX (HW*HW)    // 57600

__device__ __forceinline__ float2 cmul(float2 a, float2 b){
    return make_float2(a.x*b.x - a.y*b.y, a.x*b.y + a.y*b.x);
}
__device__ __forceinline__ float2 cadd(float2 a, float2 b){
    return make_float2(a.x+b.x, a.y+b.y);
}

// Cooperative 240-point FFT for 16 rows at once.
// Layout: blockDim = 256; rl = tid>>4 (local row 0..15), b = tid&15.
// Caller loads v[a] = x[16a + b] (15 complex values) for its row.
// On return, sm[rl][k] holds X[k], k = 0..239.
// Decomposition: n = 16a+b, k = 15m+d:
//   Y_b[d]    = sum_a v[a] * W15^{a d}          (per-thread 15-pt DFT)
//   T_b[d]    = Y_b[d] * W240^{b d}             (twiddle)
//   X[15m+d]  = sum_b T_b[d] * W16^{m b}        (per-thread 16-pt DFT, thread d)
template<int SIGN>
__device__ void fft240(float2 (*sm)[PITCH], float2* v, int rl, int b){
    const float TWOPI = 6.28318530717958647692f;
    // 15-point twiddle table
    float2 w15[15];
    #pragma unroll
    for (int t = 0; t < 15; ++t){
        float ang = (float)SIGN * TWOPI * (float)t * (1.0f/15.0f);
        __sincosf(ang, &w15[t].y, &w15[t].x);
    }
    // inter-stage twiddle: step = e^{SIGN*2pi*i*b/240}, tw walks W240^{b d}
    float2 step, tw = make_float2(1.0f, 0.0f);
    {
        float ang = (float)SIGN * TWOPI * (float)b * (1.0f/240.0f);
        __sincosf(ang, &step.y, &step.x);
    }
    for (int d = 0; d < 15; ++d){
        float2 acc = v[0];
        int idx = 0;
        #pragma unroll
        for (int a = 1; a < 15; ++a){
            idx += d; if (idx >= 15) idx -= 15;   // (a*d) % 15
            acc = cadd(acc, cmul(v[a], w15[idx]));
        }
        sm[rl][b*15 + d] = cmul(acc, tw);
        tw = cmul(tw, step);
    }
    __syncthreads();

    // stage 2: thread b (acting as d, b<15) gathers T_{b'}[d] for b'=0..15
    float2 Z[16];
    if (b < 15){
        #pragma unroll
        for (int bb = 0; bb < 16; ++bb) Z[bb] = sm[rl][bb*15 + b];
    }
    __syncthreads();   // all reads done before overwriting sm with X
    if (b < 15){
        float2 w16[16];
        #pragma unroll
        for (int t = 0; t < 16; ++t){
            float ang = (float)SIGN * TWOPI * (float)t * (1.0f/16.0f);
            __sincosf(ang, &w16[t].y, &w16[t].x);
        }
        for (int m = 0; m < 16; ++m){
            float2 acc = Z[0];
            int idx = 0;
            #pragma unroll
            for (int bb = 1; bb < 16; ++bb){
                idx += m; idx &= 15;              // (m*bb) % 16
                acc = cadd(acc, cmul(Z[bb], w16[idx]));
            }
            sm[rl][15*m + b] = acc;               // X[15m+d], d = b
        }
    }
    __syncthreads();
}

// Pass 1: forward FFT along w of real x2; write transposed: out[b][k_w][h]
__global__ __launch_bounds__(256) void pass1_rowfft(const float* __restrict__ x,
                                                    float2* __restrict__ out){
    __shared__ float2 sm[16][PITCH];
    int g = blockIdx.x, img = g / 15, row0 = (g % 15) * 16;
    int tid = threadIdx.x, rl = tid >> 4, b = tid & 15;
    const float* src = x + (size_t)img * IMG_PIX + (size_t)(row0 + rl) * HW + b;
    float2 v[15];
    #pragma unroll
    for (int a = 0; a < 15; ++a) v[a] = make_float2(src[16*a], 0.0f);
    fft240<-1>(sm, v, rl, b);
    float2* dst = out + (size_t)img * IMG_PIX;
    #pragma unroll
    for (int j = 0; j < 15; ++j){
        int k  = j*16 + (tid >> 4);
        int rr = tid & 15;
        dst[(size_t)k * HW + row0 + rr] = sm[rr][k];
    }
}

// Pass 2: forward FFT along h (rows of transposed buf, indexed by k_w);
// fuse data-consistency combine; write natural orientation z_k[b][k_h][k_w]
__global__ __launch_bounds__(256) void pass2_colfft_dc(const float2* __restrict__ in,
                                                       const float* __restrict__ under,
                                                       const float* __restrict__ Am,
                                                       float2* __restrict__ out){
    __shared__ float2 sm[16][PITCH];
    int g = blockIdx.x, img = g / 15, row0 = (g % 15) * 16;   // row0 = base k_w
    int tid = threadIdx.x, rl = tid >> 4, b = tid & 15;
    const float2* src = in + (size_t)img * IMG_PIX + (size_t)(row0 + rl) * HW + b;
    float2 v[15];
    #pragma unroll
    for (int a = 0; a < 15; ++a) v[a] = src[16*a];
    fft240<-1>(sm, v, rl, b);
    const float* ub = under + (size_t)img * (2*IMG_PIX);
    float2* dst = out + (size_t)img * IMG_PIX;
    #pragma unroll
    for (int j = 0; j < 15; ++j){
        int kh = j*16 + (tid >> 4);
        int rr = tid & 15;
        int kw = row0 + rr;
        float2 X = sm[rr][kh];
        size_t p = (size_t)kh * HW + kw;
        float s = 1.0f - Am[p];
        dst[p] = make_float2(s * X.x + ub[p], s * X.y + ub[IMG_PIX + p]);
    }
}

// Pass 3: inverse FFT along k_w of z_k (natural rows = k_h); write transposed [w][k_h]
__global__ __launch_bounds__(256) void pass3_rowifft(const float2* __restrict__ in,
                                                     float2* __restrict__ out){
    __shared__ float2 sm[16][PITCH];
    int g = blockIdx.x, img = g / 15, row0 = (g % 15) * 16;   // base k_h
    int tid = threadIdx.x, rl = tid >> 4, b = tid & 15;
    const float2* src = in + (size_t)img * IMG_PIX + (size_t)(row0 + rl) * HW + b;
    float2 v[15];
    #pragma unroll
    for (int a = 0; a < 15; ++a) v[a] = src[16*a];
    fft240<+1>(sm, v, rl, b);
    float2* dst = out + (size_t)img * IMG_PIX;
    #pragma unroll
    for (int j = 0; j < 15; ++j){
        int w  = j*16 + (tid >> 4);
        int rr = tid & 15;
        dst[(size_t)w * HW + row0 + rr] = sm[rr][w];
    }
}

// Pass 4: inverse FFT along k_h (rows of [w][k_h] buf, indexed by w);
// abs + 1/(H*W) scale; write natural out[b][h][w]
__global__ __launch_bounds__(256) void pass4_colifft_abs(const float2* __restrict__ in,
                                                         float* __restrict__ out){
    __shared__ float2 sm[16][PITCH];
    int g = blockIdx.x, img = g / 15, row0 = (g % 15) * 16;   // base w
    int tid = threadIdx.x, rl = tid >> 4, b = tid & 15;
    const float2* src = in + (size_t)img * IMG_PIX + (size_t)(row0 + rl) * HW + b;
    float2 v[15];
    #pragma unroll
    for (int a = 0; a < 15; ++a) v[a] = src[16*a];
    fft240<+1>(sm, v, rl, b);
    float* dst = out + (size_t)img * IMG_PIX;
    const float scale = 1.0f / (float)IMG_PIX;
    #pragma unroll
    for (int j = 0; j < 15; ++j){
        int h  = j*16 + (tid >> 4);
        int rr = tid & 15;
        int w  = row0 + rr;
        float2 X = sm[rr][h];
        dst[(size_t)h * HW + w] = sqrtf(X.x*X.x + X.y*X.y) * scale;
    }
}

extern "C" void kernel_launch(void* const* d_in, const int* in_sizes, int n_in,
                              void* d_out, int out_size, void* d_ws, size_t ws_size,
                              hipStream_t stream){
    const float* T2   = (const float*)d_in[0];   // [256,1,240,240] f32
    const float* U    = (const float*)d_in[1];   // [256,2,240,240] f32
    const float* Am   = (const float*)d_in[2];   // [240,240] f32
    float* out        = (float*)d_out;           // [256,1,240,240] f32

    const int B = 256;
    float2* s1 = (float2*)d_ws;                      // B*57600 complex = 118 MB
    float2* s2 = s1 + (size_t)B * IMG_PIX;           // second 118 MB

    dim3 grid(B * 15), block(256);
    pass1_rowfft    <<<grid, block, 0, stream>>>(T2, s1);
    pass2_colfft_dc <<<grid, block, 0, stream>>>(s1, U, Am, s2);
    pass3_rowifft   <<<grid, block, 0, stream>>>(s2, s1);
    pass4_colifft_abs<<<grid, block, 0, stream>>>(s1, out);
}

// Round 2
// 402.924 us; speedup vs baseline: 1.0356x; 1.0356x over previous
//
#include <hip/hip_runtime.h>
#include <math.h>

#define HW 240
#define PITCH 241          // +1 complex pad to break LDS bank conflicts on transposed reads
#define IMG_PIX (HW*HW)    // 57600

__device__ __forceinline__ float2 cmul(float2 a, float2 b){
    return make_float2(a.x*b.x - a.y*b.y, a.x*b.y + a.y*b.x);
}
__device__ __forceinline__ float2 cadd(float2 a, float2 b){
    return make_float2(a.x+b.x, a.y+b.y);
}

// Cooperative 240-point FFT for 16 rows at once.
// blockDim = 256; rl = tid>>4 (local row 0..15), b = tid&15.
// Caller loads v[a] = x[16a + b]. On return sm[rl][k] = X[k], k=0..239.
// n = 16a+b, k = 15m+d:
//   Y_b[d]   = sum_a v[a] * W15^{a d}     (per-thread 15-pt DFT)
//   T_b[d]   = Y_b[d] * W240^{b d}        (twiddle)
//   X[15m+d] = sum_b T_b[d] * W16^{m b}   (per-thread 16-pt DFT, thread d)
template<int SIGN>
__device__ void fft240(float2 (*sm)[PITCH], float2* v, int rl, int b){
    const float TWOPI = 6.28318530717958647692f;
    float2 w15[15];
    #pragma unroll
    for (int t = 0; t < 15; ++t){
        float ang = (float)SIGN * TWOPI * (float)t * (1.0f/15.0f);
        __sincosf(ang, &w15[t].y, &w15[t].x);
    }
    float2 step, tw = make_float2(1.0f, 0.0f);
    {
        float ang = (float)SIGN * TWOPI * (float)b * (1.0f/240.0f);
        __sincosf(ang, &step.y, &step.x);
    }
    for (int d = 0; d < 15; ++d){
        float2 acc = v[0];
        int idx = 0;
        #pragma unroll
        for (int a = 1; a < 15; ++a){
            idx += d; if (idx >= 15) idx -= 15;   // (a*d) % 15
            acc = cadd(acc, cmul(v[a], w15[idx]));
        }
        sm[rl][b*15 + d] = cmul(acc, tw);
        tw = cmul(tw, step);
    }
    __syncthreads();

    float2 Z[16];
    if (b < 15){
        #pragma unroll
        for (int bb = 0; bb < 16; ++bb) Z[bb] = sm[rl][bb*15 + b];
    }
    __syncthreads();
    if (b < 15){
        float2 w16[16];
        #pragma unroll
        for (int t = 0; t < 16; ++t){
            float ang = (float)SIGN * TWOPI * (float)t * (1.0f/16.0f);
            __sincosf(ang, &w16[t].y, &w16[t].x);
        }
        for (int m = 0; m < 16; ++m){
            float2 acc = Z[0];
            int idx = 0;
            #pragma unroll
            for (int bb = 1; bb < 16; ++bb){
                idx += m; idx &= 15;              // (m*bb) % 16
                acc = cadd(acc, cmul(Z[bb], w16[idx]));
            }
            sm[rl][15*m + b] = acc;               // X[15m+d], d = b
        }
    }
    __syncthreads();
}

// Pass A: forward FFT along w of real x2; write transposed: out[b][k_w][h]
__global__ __launch_bounds__(256) void passA_rowfft(const float* __restrict__ x,
                                                    float2* __restrict__ out){
    __shared__ float2 sm[16][PITCH];
    int g = blockIdx.x, img = g / 15, row0 = (g % 15) * 16;
    int tid = threadIdx.x, rl = tid >> 4, b = tid & 15;
    const float* src = x + (size_t)img * IMG_PIX + (size_t)(row0 + rl) * HW + b;
    float2 v[15];
    #pragma unroll
    for (int a = 0; a < 15; ++a) v[a] = make_float2(src[16*a], 0.0f);
    fft240<-1>(sm, v, rl, b);
    float2* dst = out + (size_t)img * IMG_PIX;
    #pragma unroll
    for (int j = 0; j < 15; ++j){
        int k  = j*16 + rl;
        dst[(size_t)k * HW + row0 + b] = sm[b][k];
    }
}

// Pass B (fused): for a slab of 16 k_w columns —
//   forward FFT along h  ->  X[kh]
//   data-consistency combine in LDS:  z = (1-A)*X + y_k
//   inverse FFT along kh ->  Z2[h]   (unnormalized)
// write transposed: out[b][h][k_w]
__global__ __launch_bounds__(256) void passB_col_dc_icol(const float2* __restrict__ in,
                                                         const float* __restrict__ under,
                                                         const float* __restrict__ Am,
                                                         float2* __restrict__ out){
    __shared__ float2 sm[16][PITCH];
    int g = blockIdx.x, img = g / 15, row0 = (g % 15) * 16;   // base k_w
    int tid = threadIdx.x, rl = tid >> 4, b = tid & 15;
    const float2* src = in + (size_t)img * IMG_PIX + (size_t)(row0 + rl) * HW + b;
    float2 v[15];
    #pragma unroll
    for (int a = 0; a < 15; ++a) v[a] = src[16*a];
    fft240<-1>(sm, v, rl, b);                 // sm[c][kh] = X[kh] for kw=row0+c

    // combine in LDS, coalesced global reads: thread (rl,b) handles (kh=j*16+rl, kw=row0+b)
    const float* y0 = under + (size_t)img * (2*IMG_PIX);
    const float* y1 = y0 + IMG_PIX;
    #pragma unroll
    for (int j = 0; j < 15; ++j){
        int kh = j*16 + rl;
        size_t p = (size_t)kh * HW + row0 + b;
        float s = 1.0f - Am[p];
        float2 X = sm[b][kh];
        sm[b][kh] = make_float2(s * X.x + y0[p], s * X.y + y1[p]);
    }
    __syncthreads();
    // gather inverse-FFT inputs: v[a] = z[16a+b] for column rl
    #pragma unroll
    for (int a = 0; a < 15; ++a) v[a] = sm[rl][16*a + b];
    __syncthreads();                          // all gathers done before fft240 scribbles sm
    fft240<+1>(sm, v, rl, b);                 // sm[c][h] = Z2[h] for kw=row0+c

    // write transposed for pass C: out[img][h][kw]
    float2* dst = out + (size_t)img * IMG_PIX;
    #pragma unroll
    for (int j = 0; j < 15; ++j){
        int h = j*16 + rl;
        dst[(size_t)h * HW + row0 + b] = sm[b][h];
    }
}

// Pass C: inverse FFT along k_w for each row h; abs + 1/(H*W); natural out[b][h][w]
__global__ __launch_bounds__(256) void passC_irow_abs(const float2* __restrict__ in,
                                                      float* __restrict__ out){
    __shared__ float2 sm[16][PITCH];
    int g = blockIdx.x, img = g / 15, row0 = (g % 15) * 16;   // base h
    int tid = threadIdx.x, rl = tid >> 4, b = tid & 15;
    const float2* src = in + (size_t)img * IMG_PIX + (size_t)(row0 + rl) * HW + b;
    float2 v[15];
    #pragma unroll
    for (int a = 0; a < 15; ++a) v[a] = src[16*a];
    fft240<+1>(sm, v, rl, b);                 // sm[r][w] = Z[w] for h=row0+r
    float* dst = out + (size_t)img * IMG_PIX;
    const float scale = 1.0f / (float)IMG_PIX;
    #pragma unroll
    for (int j = 0; j < 15; ++j){
        int w = j*16 + b;
        float2 X = sm[rl][w];
        dst[(size_t)(row0 + rl) * HW + w] = sqrtf(X.x*X.x + X.y*X.y) * scale;
    }
}

extern "C" void kernel_launch(void* const* d_in, const int* in_sizes, int n_in,
                              void* d_out, int out_size, void* d_ws, size_t ws_size,
                              hipStream_t stream){
    const float* T2   = (const float*)d_in[0];   // [256,1,240,240] f32
    const float* U    = (const float*)d_in[1];   // [256,2,240,240] f32
    const float* Am   = (const float*)d_in[2];   // [240,240] f32
    float* out        = (float*)d_out;           // [256,1,240,240] f32

    const int B = 256;
    float2* s1 = (float2*)d_ws;                      // B*57600 complex = 118 MB
    float2* s2 = s1 + (size_t)B * IMG_PIX;           // second 118 MB

    dim3 grid(B * 15), block(256);
    passA_rowfft     <<<grid, block, 0, stream>>>(T2, s1);
    passB_col_dc_icol<<<grid, block, 0, stream>>>(s1, U, Am, s2);
    passC_irow_abs   <<<grid, block, 0, stream>>>(s1 == s2 ? s1 : s2, out);
}

// Round 3
// 313.355 us; speedup vs baseline: 1.3316x; 1.2858x over previous
//
#include <hip/hip_runtime.h>
#include <math.h>

#define HW 240
#define PITCH 241          // +1 complex pad to break LDS bank conflicts on transposed reads
#define IMG_PIX (HW*HW)    // 57600

__device__ __forceinline__ float2 cmul(float2 a, float2 b){
    return make_float2(a.x*b.x - a.y*b.y, a.x*b.y + a.y*b.x);
}
__device__ __forceinline__ float2 cadd(float2 a, float2 b){
    return make_float2(a.x+b.x, a.y+b.y);
}
__device__ __forceinline__ float2 csub(float2 a, float2 b){
    return make_float2(a.x-b.x, a.y-b.y);
}

// ---------- 15-point DFT via Cooley-Tukey 3x5, all-constant twiddles ----------
// Convention: X[k] = sum_n x[n] e^{SIGN*2*pi*i*n*k/15}
// n = 5*n1 + n2 (n1<3, n2<5), k = k1 + 3*k2 (k1<3, k2<5)
template<int SIGN>
__device__ __forceinline__ void dft15(const float2* x, float2* X){
    const float S = (float)SIGN;
    const float s3 = 0.8660254037844387f;
    float2 y[5][3];
    #pragma unroll
    for (int n2 = 0; n2 < 5; ++n2){
        float2 a0 = x[n2], a1 = x[5+n2], a2 = x[10+n2];
        float2 t = cadd(a1, a2);
        float2 u = csub(a1, a2);
        float2 m = make_float2(a0.x - 0.5f*t.x, a0.y - 0.5f*t.y);
        float sx = S * s3;
        float2 s = make_float2(-sx*u.y, sx*u.x);   // i*sigma*s3*u
        y[n2][0] = cadd(a0, t);
        y[n2][1] = cadd(m, s);
        y[n2][2] = csub(m, s);
    }
    // twiddle by W15^{n2*k1}, exponents 1..8
    const float C15[9] = {1.f, 0.9135454576426009f, 0.6691306063588582f, 0.30901699437494745f,
                          -0.10452846326765346f, -0.5f, -0.8090169943749475f,
                          -0.9781476007338057f, -0.9781476007338057f};
    const float S15[9] = {0.f, 0.4067366430758004f, 0.7431448254773942f, 0.9510565162951535f,
                          0.9945218953682733f, 0.8660254037844387f, 0.5877852522924731f,
                          0.20791169081775931f, -0.20791169081775931f};
    #pragma unroll
    for (int n2 = 1; n2 < 5; ++n2){
        #pragma unroll
        for (int k1 = 1; k1 < 3; ++k1){
            const int e = n2*k1;
            y[n2][k1] = cmul(y[n2][k1], make_float2(C15[e], S*S15[e]));
        }
    }
    // 5-pt DFT over n2 for each k1
    const float c1 = 0.30901699437494745f, s1 = 0.9510565162951535f;
    const float c2 = -0.8090169943749475f, s2 = 0.5877852522924731f;
    #pragma unroll
    for (int k1 = 0; k1 < 3; ++k1){
        float2 x0 = y[0][k1], x1 = y[1][k1], x2 = y[2][k1], x3 = y[3][k1], x4 = y[4][k1];
        float2 t1 = cadd(x1, x4), t3 = csub(x1, x4);
        float2 t2 = cadd(x2, x3), t4 = csub(x2, x3);
        X[k1] = make_float2(x0.x + t1.x + t2.x, x0.y + t1.y + t2.y);
        float2 u1 = make_float2(x0.x + c1*t1.x + c2*t2.x, x0.y + c1*t1.y + c2*t2.y);
        float2 u2 = make_float2(x0.x + c2*t1.x + c1*t2.x, x0.y + c2*t1.y + c1*t2.y);
        float2 v1 = make_float2(S*(s1*t3.x + s2*t4.x), S*(s1*t3.y + s2*t4.y));
        float2 v2 = make_float2(S*(s2*t3.x - s1*t4.x), S*(s2*t3.y - s1*t4.y));
        X[k1+3]  = make_float2(u1.x - v1.y, u1.y + v1.x);   // k2=1
        X[k1+12] = make_float2(u1.x + v1.y, u1.y - v1.x);   // k2=4
        X[k1+6]  = make_float2(u2.x - v2.y, u2.y + v2.x);   // k2=2
        X[k1+9]  = make_float2(u2.x + v2.y, u2.y - v2.x);   // k2=3
    }
}

// ---------- 16-point DFT via radix-4 x radix-4, all-constant twiddles ----------
// n = 4*n1 + n2, k = k1 + 4*k2
template<int SIGN>
__device__ __forceinline__ void dft16(const float2* x, float2* X){
    const float S = (float)SIGN;
    float2 y[4][4];
    #pragma unroll
    for (int n2 = 0; n2 < 4; ++n2){
        float2 a0 = x[n2], a1 = x[4+n2], a2 = x[8+n2], a3 = x[12+n2];
        float2 t0 = cadd(a0,a2), t1 = csub(a0,a2);
        float2 t2 = cadd(a1,a3), t3 = csub(a1,a3);
        float2 it3 = make_float2(-S*t3.y, S*t3.x);
        y[n2][0] = cadd(t0,t2);
        y[n2][2] = csub(t0,t2);
        y[n2][1] = cadd(t1,it3);
        y[n2][3] = csub(t1,it3);
    }
    const float C16[10] = {1.f, 0.9238795325112867f, 0.7071067811865476f, 0.3826834323650898f,
                           0.f, -0.3826834323650898f, -0.7071067811865476f, -0.9238795325112867f,
                           -1.f, -0.9238795325112867f};
    const float S16[10] = {0.f, 0.3826834323650898f, 0.7071067811865476f, 0.9238795325112867f,
                           1.f, 0.9238795325112867f, 0.7071067811865476f, 0.3826834323650898f,
                           0.f, -0.3826834323650898f};
    #pragma unroll
    for (int n2 = 1; n2 < 4; ++n2){
        #pragma unroll
        for (int k1 = 1; k1 < 4; ++k1){
            const int e = n2*k1;
            y[n2][k1] = cmul(y[n2][k1], make_float2(C16[e], S*S16[e]));
        }
    }
    #pragma unroll
    for (int k1 = 0; k1 < 4; ++k1){
        float2 a0 = y[0][k1], a1 = y[1][k1], a2 = y[2][k1], a3 = y[3][k1];
        float2 t0 = cadd(a0,a2), t1 = csub(a0,a2);
        float2 t2 = cadd(a1,a3), t3 = csub(a1,a3);
        float2 it3 = make_float2(-S*t3.y, S*t3.x);
        X[k1]    = cadd(t0,t2);
        X[k1+8]  = csub(t0,t2);
        X[k1+4]  = cadd(t1,it3);
        X[k1+12] = csub(t1,it3);
    }
}

// Cooperative 240-point FFT for 16 rows at once.
// blockDim = 256; rl = tid>>4 (local row 0..15), b = tid&15.
// Caller loads v[a] = x[16a + b]. On return sm[rl][k] = X[k], k=0..239.
template<int SIGN>
__device__ void fft240(float2 (*sm)[PITCH], float2* v, int rl, int b){
    const float TWOPI = 6.28318530717958647692f;
    float2 Y[15];
    dft15<SIGN>(v, Y);
    // inter-stage twiddle: W240^{b*d}, walked from a single sincos
    float2 step, tw = make_float2(1.0f, 0.0f);
    {
        float ang = (float)SIGN * TWOPI * (float)b * (1.0f/240.0f);
        __sincosf(ang, &step.y, &step.x);
    }
    #pragma unroll
    for (int d = 0; d < 15; ++d){
        sm[rl][b*15 + d] = cmul(Y[d], tw);
        tw = cmul(tw, step);
    }
    __syncthreads();

    float2 Z[16];
    if (b < 15){
        #pragma unroll
        for (int bb = 0; bb < 16; ++bb) Z[bb] = sm[rl][bb*15 + b];
    }
    __syncthreads();
    if (b < 15){
        float2 XX[16];
        dft16<SIGN>(Z, XX);
        #pragma unroll
        for (int m = 0; m < 16; ++m) sm[rl][15*m + b] = XX[m];   // X[15m+d], d=b
    }
    __syncthreads();
}

// Pass A: forward FFT along w of real x2; write transposed: out[b][k_w][h]
__global__ __launch_bounds__(256) void passA_rowfft(const float* __restrict__ x,
                                                    float2* __restrict__ out){
    __shared__ float2 sm[16][PITCH];
    int g = blockIdx.x, img = g / 15, row0 = (g % 15) * 16;
    int tid = threadIdx.x, rl = tid >> 4, b = tid & 15;
    const float* src = x + (size_t)img * IMG_PIX + (size_t)(row0 + rl) * HW + b;
    float2 v[15];
    #pragma unroll
    for (int a = 0; a < 15; ++a) v[a] = make_float2(src[16*a], 0.0f);
    fft240<-1>(sm, v, rl, b);
    float2* dst = out + (size_t)img * IMG_PIX;
    #pragma unroll
    for (int j = 0; j < 15; ++j){
        int k  = j*16 + rl;
        dst[(size_t)k * HW + row0 + b] = sm[b][k];
    }
}

// Pass B (fused): forward FFT along h -> combine in LDS -> inverse FFT along kh;
// write transposed: out[b][h][k_w]
__global__ __launch_bounds__(256) void passB_col_dc_icol(const float2* __restrict__ in,
                                                         const float* __restrict__ under,
                                                         const float* __restrict__ Am,
                                                         float2* __restrict__ out){
    __shared__ float2 sm[16][PITCH];
    int g = blockIdx.x, img = g / 15, row0 = (g % 15) * 16;   // base k_w
    int tid = threadIdx.x, rl = tid >> 4, b = tid & 15;
    const float2* src = in + (size_t)img * IMG_PIX + (size_t)(row0 + rl) * HW + b;
    float2 v[15];
    #pragma unroll
    for (int a = 0; a < 15; ++a) v[a] = src[16*a];
    fft240<-1>(sm, v, rl, b);                 // sm[c][kh] = X[kh] for kw=row0+c

    const float* y0 = under + (size_t)img * (2*IMG_PIX);
    const float* y1 = y0 + IMG_PIX;
    #pragma unroll
    for (int j = 0; j < 15; ++j){
        int kh = j*16 + rl;
        size_t p = (size_t)kh * HW + row0 + b;
        float s = 1.0f - Am[p];
        float2 X = sm[b][kh];
        sm[b][kh] = make_float2(s * X.x + y0[p], s * X.y + y1[p]);
    }
    __syncthreads();
    #pragma unroll
    for (int a = 0; a < 15; ++a) v[a] = sm[rl][16*a + b];
    __syncthreads();
    fft240<+1>(sm, v, rl, b);                 // sm[c][h] = Z2[h] for kw=row0+c

    float2* dst = out + (size_t)img * IMG_PIX;
    #pragma unroll
    for (int j = 0; j < 15; ++j){
        int h = j*16 + rl;
        dst[(size_t)h * HW + row0 + b] = sm[b][h];
    }
}

// Pass C: inverse FFT along k_w; abs + 1/(H*W); natural out[b][h][w]
__global__ __launch_bounds__(256) void passC_irow_abs(const float2* __restrict__ in,
                                                      float* __restrict__ out){
    __shared__ float2 sm[16][PITCH];
    int g = blockIdx.x, img = g / 15, row0 = (g % 15) * 16;   // base h
    int tid = threadIdx.x, rl = tid >> 4, b = tid & 15;
    const float2* src = in + (size_t)img * IMG_PIX + (size_t)(row0 + rl) * HW + b;
    float2 v[15];
    #pragma unroll
    for (int a = 0; a < 15; ++a) v[a] = src[16*a];
    fft240<+1>(sm, v, rl, b);                 // sm[r][w] = Z[w] for h=row0+r
    float* dst = out + (size_t)img * IMG_PIX;
    const float scale = 1.0f / (float)IMG_PIX;
    #pragma unroll
    for (int j = 0; j < 15; ++j){
        int w = j*16 + b;
        float2 X = sm[rl][w];
        dst[(size_t)(row0 + rl) * HW + w] = sqrtf(X.x*X.x + X.y*X.y) * scale;
    }
}

extern "C" void kernel_launch(void* const* d_in, const int* in_sizes, int n_in,
                              void* d_out, int out_size, void* d_ws, size_t ws_size,
                              hipStream_t stream){
    const float* T2   = (const float*)d_in[0];   // [256,1,240,240] f32
    const float* U    = (const float*)d_in[1];   // [256,2,240,240] f32
    const float* Am   = (const float*)d_in[2];   // [240,240] f32
    float* out        = (float*)d_out;           // [256,1,240,240] f32

    const int B = 256;
    float2* s1 = (float2*)d_ws;                      // B*57600 complex = 118 MB
    float2* s2 = s1 + (size_t)B * IMG_PIX;           // second 118 MB

    dim3 grid(B * 15), block(256);
    passA_rowfft     <<<grid, block, 0, stream>>>(T2, s1);
    passB_col_dc_icol<<<grid, block, 0, stream>>>(s1, U, Am, s2);
    passC_irow_abs   <<<grid, block, 0, stream>>>(s2, out);
}

// Round 4
// 283.619 us; speedup vs baseline: 1.4712x; 1.1048x over previous
//
#include <hip/hip_runtime.h>
#include <hip/hip_fp16.h>
#include <math.h>

#define HW 240
#define PITCH 241          // +1 complex pad on LDS rows
#define IMG_PIX (HW*HW)    // 57600
#define NB 15              // kw blocks per image
#define TILE_ELEMS (240*16) // 3840 elements per blocked chunk

__device__ __forceinline__ float2 cmul(float2 a, float2 b){
    return make_float2(a.x*b.x - a.y*b.y, a.x*b.y + a.y*b.x);
}
__device__ __forceinline__ float2 cadd(float2 a, float2 b){
    return make_float2(a.x+b.x, a.y+b.y);
}
__device__ __forceinline__ float2 csub(float2 a, float2 b){
    return make_float2(a.x-b.x, a.y-b.y);
}
__device__ __forceinline__ __half2 f2h(float2 a){ return __floats2half2_rn(a.x, a.y); }
__device__ __forceinline__ float2 h2f(__half2 h){ return make_float2(__low2float(h), __high2float(h)); }

// ---------- 15-point DFT via Cooley-Tukey 3x5, all-constant twiddles ----------
template<int SIGN>
__device__ __forceinline__ void dft15(const float2* x, float2* X){
    const float S = (float)SIGN;
    const float s3 = 0.8660254037844387f;
    float2 y[5][3];
    #pragma unroll
    for (int n2 = 0; n2 < 5; ++n2){
        float2 a0 = x[n2], a1 = x[5+n2], a2 = x[10+n2];
        float2 t = cadd(a1, a2);
        float2 u = csub(a1, a2);
        float2 m = make_float2(a0.x - 0.5f*t.x, a0.y - 0.5f*t.y);
        float sx = S * s3;
        float2 s = make_float2(-sx*u.y, sx*u.x);
        y[n2][0] = cadd(a0, t);
        y[n2][1] = cadd(m, s);
        y[n2][2] = csub(m, s);
    }
    const float C15[9] = {1.f, 0.9135454576426009f, 0.6691306063588582f, 0.30901699437494745f,
                          -0.10452846326765346f, -0.5f, -0.8090169943749475f,
                          -0.9781476007338057f, -0.9781476007338057f};
    const float S15[9] = {0.f, 0.4067366430758004f, 0.7431448254773942f, 0.9510565162951535f,
                          0.9945218953682733f, 0.8660254037844387f, 0.5877852522924731f,
                          0.20791169081775931f, -0.20791169081775931f};
    #pragma unroll
    for (int n2 = 1; n2 < 5; ++n2){
        #pragma unroll
        for (int k1 = 1; k1 < 3; ++k1){
            const int e = n2*k1;
            y[n2][k1] = cmul(y[n2][k1], make_float2(C15[e], S*S15[e]));
        }
    }
    const float c1 = 0.30901699437494745f, s1 = 0.9510565162951535f;
    const float c2 = -0.8090169943749475f, s2 = 0.5877852522924731f;
    #pragma unroll
    for (int k1 = 0; k1 < 3; ++k1){
        float2 x0 = y[0][k1], x1 = y[1][k1], x2 = y[2][k1], x3 = y[3][k1], x4 = y[4][k1];
        float2 t1 = cadd(x1, x4), t3 = csub(x1, x4);
        float2 t2 = cadd(x2, x3), t4 = csub(x2, x3);
        X[k1] = make_float2(x0.x + t1.x + t2.x, x0.y + t1.y + t2.y);
        float2 u1 = make_float2(x0.x + c1*t1.x + c2*t2.x, x0.y + c1*t1.y + c2*t2.y);
        float2 u2 = make_float2(x0.x + c2*t1.x + c1*t2.x, x0.y + c2*t1.y + c1*t2.y);
        float2 v1 = make_float2(S*(s1*t3.x + s2*t4.x), S*(s1*t3.y + s2*t4.y));
        float2 v2 = make_float2(S*(s2*t3.x - s1*t4.x), S*(s2*t3.y - s1*t4.y));
        X[k1+3]  = make_float2(u1.x - v1.y, u1.y + v1.x);
        X[k1+12] = make_float2(u1.x + v1.y, u1.y - v1.x);
        X[k1+6]  = make_float2(u2.x - v2.y, u2.y + v2.x);
        X[k1+9]  = make_float2(u2.x + v2.y, u2.y - v2.x);
    }
}

// ---------- 16-point DFT via radix-4 x radix-4, all-constant twiddles ----------
template<int SIGN>
__device__ __forceinline__ void dft16(const float2* x, float2* X){
    const float S = (float)SIGN;
    float2 y[4][4];
    #pragma unroll
    for (int n2 = 0; n2 < 4; ++n2){
        float2 a0 = x[n2], a1 = x[4+n2], a2 = x[8+n2], a3 = x[12+n2];
        float2 t0 = cadd(a0,a2), t1 = csub(a0,a2);
        float2 t2 = cadd(a1,a3), t3 = csub(a1,a3);
        float2 it3 = make_float2(-S*t3.y, S*t3.x);
        y[n2][0] = cadd(t0,t2);
        y[n2][2] = csub(t0,t2);
        y[n2][1] = cadd(t1,it3);
        y[n2][3] = csub(t1,it3);
    }
    const float C16[10] = {1.f, 0.9238795325112867f, 0.7071067811865476f, 0.3826834323650898f,
                           0.f, -0.3826834323650898f, -0.7071067811865476f, -0.9238795325112867f,
                           -1.f, -0.9238795325112867f};
    const float S16[10] = {0.f, 0.3826834323650898f, 0.7071067811865476f, 0.9238795325112867f,
                           1.f, 0.9238795325112867f, 0.7071067811865476f, 0.3826834323650898f,
                           0.f, -0.3826834323650898f};
    #pragma unroll
    for (int n2 = 1; n2 < 4; ++n2){
        #pragma unroll
        for (int k1 = 1; k1 < 4; ++k1){
            const int e = n2*k1;
            y[n2][k1] = cmul(y[n2][k1], make_float2(C16[e], S*S16[e]));
        }
    }
    #pragma unroll
    for (int k1 = 0; k1 < 4; ++k1){
        float2 a0 = y[0][k1], a1 = y[1][k1], a2 = y[2][k1], a3 = y[3][k1];
        float2 t0 = cadd(a0,a2), t1 = csub(a0,a2);
        float2 t2 = cadd(a1,a3), t3 = csub(a1,a3);
        float2 it3 = make_float2(-S*t3.y, S*t3.x);
        X[k1]    = cadd(t0,t2);
        X[k1+8]  = csub(t0,t2);
        X[k1+4]  = cadd(t1,it3);
        X[k1+12] = csub(t1,it3);
    }
}

// Cooperative 240-point FFT for 16 rows at once. v[a] = x[16a+b] preloaded.
// On return sm[rl][k] = X[k]. 3 internal barriers.
template<int SIGN>
__device__ void fft240(float2 (*sm)[PITCH], float2* v, int rl, int b){
    const float TWOPI = 6.28318530717958647692f;
    float2 Y[15];
    dft15<SIGN>(v, Y);
    float2 step, tw = make_float2(1.0f, 0.0f);
    {
        float ang = (float)SIGN * TWOPI * (float)b * (1.0f/240.0f);
        __sincosf(ang, &step.y, &step.x);
    }
    #pragma unroll
    for (int d = 0; d < 15; ++d){
        sm[rl][b*15 + d] = cmul(Y[d], tw);
        tw = cmul(tw, step);
    }
    __syncthreads();

    float2 Z[16];
    if (b < 15){
        #pragma unroll
        for (int bb = 0; bb < 16; ++bb) Z[bb] = sm[rl][bb*15 + b];
    }
    __syncthreads();
    if (b < 15){
        float2 XX[16];
        dft16<SIGN>(Z, XX);
        #pragma unroll
        for (int m = 0; m < 16; ++m) sm[rl][15*m + b] = XX[m];
    }
    __syncthreads();
}

// Pass A: flat-load 16 rows of real x -> LDS; row FFT; store fp16 blocked:
// inter1[((img*15+kb)*240 + h)*16 + kwin],  kw = kb*16+kwin
__global__ __launch_bounds__(256) void passA_rowfft(const float* __restrict__ x,
                                                    __half2* __restrict__ out){
    __shared__ float2 sm[16][PITCH];
    float* smf = (float*)sm;                 // float pitch = 2*PITCH = 482
    int g = blockIdx.x, img = g / NB, h0 = (g % NB) * 16;
    int tid = threadIdx.x, rl = tid >> 4, b = tid & 15;
    const float* src = x + (size_t)img * IMG_PIX + (size_t)h0 * HW;
    #pragma unroll
    for (int j = 0; j < 15; ++j){
        int f = j*256 + tid;
        smf[(f/HW)*(2*PITCH) + (f%HW)] = src[f];   // contiguous 1 KB / wave-instr
    }
    __syncthreads();
    float2 v[15];
    #pragma unroll
    for (int a = 0; a < 15; ++a) v[a] = make_float2(smf[rl*(2*PITCH) + 16*a + b], 0.0f);
    __syncthreads();                          // all gathers done before fft scribbles sm
    fft240<-1>(sm, v, rl, b);                 // sm[r][kw], r = local h
    int hl = rl, kwin = b;
    #pragma unroll
    for (int kb = 0; kb < NB; ++kb){
        float2 val = sm[hl][kb*16 + kwin];
        out[((size_t)(img*NB + kb)*HW + h0 + hl)*16 + kwin] = f2h(val);
    }
}

// Pass B: flat-load blocked chunk (16 kw cols x 240 h) -> col FFT ->
// combine with y_k -> inverse col FFT (x 1/240) -> store fp16 blocked chunk.
__global__ __launch_bounds__(256) void passB_col_dc_icol(const __half2* __restrict__ in,
                                                         const float* __restrict__ under,
                                                         const float* __restrict__ Am,
                                                         __half2* __restrict__ out){
    __shared__ float2 sm[16][PITCH];
    int g = blockIdx.x, img = g / NB, s = g % NB, kw0 = s * 16;
    int tid = threadIdx.x, rl = tid >> 4, b = tid & 15;
    const __half2* src = in + (size_t)(img*NB + s) * TILE_ELEMS;   // [h][c]
    #pragma unroll
    for (int j = 0; j < 15; ++j){
        int f = j*256 + tid;
        sm[f & 15][f >> 4] = h2f(src[f]);     // contiguous 256B / wave-instr
    }
    __syncthreads();
    float2 v[15];
    #pragma unroll
    for (int a = 0; a < 15; ++a) v[a] = sm[rl][16*a + b];
    __syncthreads();
    fft240<-1>(sm, v, rl, b);                 // sm[c][kh]

    const float* y0 = under + (size_t)img * (2*IMG_PIX);
    const float* y1 = y0 + IMG_PIX;
    #pragma unroll
    for (int j = 0; j < 15; ++j){
        int kh = j*16 + rl;
        size_t p = (size_t)kh * HW + kw0 + b;
        float sc = 1.0f - Am[p];
        float2 X = sm[b][kh];
        sm[b][kh] = make_float2(sc * X.x + y0[p], sc * X.y + y1[p]);
    }
    __syncthreads();
    #pragma unroll
    for (int a = 0; a < 15; ++a) v[a] = sm[rl][16*a + b];
    __syncthreads();
    fft240<+1>(sm, v, rl, b);                 // sm[c][h]

    const float inv240 = 1.0f / 240.0f;
    __half2* dst = out + (size_t)(img*NB + s) * TILE_ELEMS;
    #pragma unroll
    for (int j = 0; j < 15; ++j){
        int f = j*256 + tid;
        float2 val = sm[f & 15][f >> 4];
        val.x *= inv240; val.y *= inv240;
        dst[f] = f2h(val);
    }
}

// Pass C: gather 15 blocked chunks (each contiguous 1KB) -> row tile [16 h][240 kw];
// inverse row FFT; abs * 1/240; flat store natural out.
__global__ __launch_bounds__(256) void passC_irow_abs(const __half2* __restrict__ in,
                                                      float* __restrict__ outp){
    __shared__ float2 sm[16][PITCH];
    int g = blockIdx.x, img = g / NB, h0 = (g % NB) * 16;
    int tid = threadIdx.x, rl = tid >> 4, b = tid & 15;
    int hl = rl, kwin = b;
    #pragma unroll
    for (int kb = 0; kb < NB; ++kb){
        __half2 hv = in[((size_t)(img*NB + kb)*HW + h0 + hl)*16 + kwin];
        sm[hl][kb*16 + kwin] = h2f(hv);
    }
    __syncthreads();
    float2 v[15];
    #pragma unroll
    for (int a = 0; a < 15; ++a) v[a] = sm[rl][16*a + b];
    __syncthreads();
    fft240<+1>(sm, v, rl, b);                 // sm[r][w]
    float* dst = outp + (size_t)img * IMG_PIX + (size_t)h0 * HW;
    const float inv240 = 1.0f / 240.0f;
    #pragma unroll
    for (int j = 0; j < 15; ++j){
        int f = j*256 + tid;
        float2 X = sm[f/HW][f%HW];
        dst[f] = sqrtf(X.x*X.x + X.y*X.y) * inv240;
    }
}

extern "C" void kernel_launch(void* const* d_in, const int* in_sizes, int n_in,
                              void* d_out, int out_size, void* d_ws, size_t ws_size,
                              hipStream_t stream){
    const float* T2   = (const float*)d_in[0];   // [256,1,240,240] f32
    const float* U    = (const float*)d_in[1];   // [256,2,240,240] f32
    const float* Am   = (const float*)d_in[2];   // [240,240] f32
    float* out        = (float*)d_out;           // [256,1,240,240] f32

    const int B = 256;
    __half2* i1 = (__half2*)d_ws;                        // B*57600 half2 = 59 MB
    __half2* i2 = i1 + (size_t)B * IMG_PIX;              // second 59 MB

    dim3 grid(B * NB), block(256);
    passA_rowfft     <<<grid, block, 0, stream>>>(T2, i1);
    passB_col_dc_icol<<<grid, block, 0, stream>>>(i1, U, Am, i2);
    passC_irow_abs   <<<grid, block, 0, stream>>>(i2, out);
}